// Round 1
// baseline (400.418 us; speedup 1.0000x reference)
//
#include <hip/hip_runtime.h>

// Problem constants (fixed by setup_inputs):
//   x: (64, 4, 2, 256, 256) f32 ; tensors: (4,4,128,128,2,2,2,2,2) f32 ;
//   bias: (4,128,128,2) f32 ; out: (64,4,2,128,128) f32
// sx=sy=256 even -> ix1=2x+1, iy1=2y+1 (clamp inert).
#define NUMN 64
#define CIN 4
#define COUT 4
#define SX 256
#define SY 256
#define NXX 128
#define NYY 128
#define YTILE 32
#define NSPLIT 2
#define NPER (NUMN / NSPLIT)

__global__ __launch_bounds__(256, 2)
void ttn_kernel(const float* __restrict__ x, const float* __restrict__ w,
                const float* __restrict__ bias, float* __restrict__ out)
{
    const int bid = blockIdx.x;
    const int xi = bid % NXX;
    const int yt = (bid / NXX) % (NYY / YTILE);
    const int ns = bid / (NXX * (NYY / YTILE));

    const int tid = threadIdx.x;
    const int yl  = tid & (YTILE - 1);
    const int po  = tid >> 5;        // 0..7 == p*2 + o
    const int p   = po >> 1;
    const int o   = po & 1;
    const int y   = yt * YTILE + yl;

    // Per-thread weights in registers: wr[c][q], q = 8i+4j+2k+l.
    // tensors idx = ((((c*COUT+p)*NXX+xi)*NYY+y)*16 + q)*2 + o
    float wr[CIN][16];
#pragma unroll
    for (int c = 0; c < CIN; ++c) {
        const float* wp = w + ((size_t)(((c*COUT + p)*NXX + xi)*NYY + y) * 16) * 2 + o;
#pragma unroll
        for (int q = 0; q < 16; ++q) wr[c][q] = wp[2*q];
    }
    const float bv = bias[(((p*NXX + xi)*NYY + y) * 2) + o];

    const int ix0 = 2*xi;
    const int ix1 = (2*xi + 1 < SX) ? (2*xi + 1) : (SX - 1);
    const int iy0 = 2*y;   // iy1 = iy0+1 (SY even, always in bounds)

    const float* xb = x + (size_t)(ns * NPER) * (CIN * 2 * SX * SY) + iy0;
    float* ob = out + (size_t)(ns * NPER) * (COUT * 2 * NXX * NYY)
                    + po * (NXX * NYY) + xi * NYY + y;

    for (int n = 0; n < NPER; ++n) {
        const float* xn = xb + (size_t)n * (CIN * 2 * SX * SY);
        float acc = bv;
#pragma unroll
        for (int c = 0; c < CIN; ++c) {
            const float* xc = xn + c * (2 * SX * SY);
            // float2 at (d, ix0, iy0) = {a_d, e_d}; at (d, ix1, iy0) = {b_d, f_d}
            const float2 ae0 = *(const float2*)(xc + (0 * SX + ix0) * SY);
            const float2 bf0 = *(const float2*)(xc + (0 * SX + ix1) * SY);
            const float2 ae1 = *(const float2*)(xc + (1 * SX + ix0) * SY);
            const float2 bf1 = *(const float2*)(xc + (1 * SX + ix1) * SY);
            const float a0 = ae0.x, e0 = ae0.y, b0 = bf0.x, f0 = bf0.y;
            const float a1 = ae1.x, e1 = ae1.y, b1 = bf1.x, f1 = bf1.y;

            const float ef00 = e0*f0, ef01 = e0*f1, ef10 = e1*f0, ef11 = e1*f1;
            const float ab00 = a0*b0, ab01 = a0*b1, ab10 = a1*b0, ab11 = a1*b1;

            const float* wq = wr[c];
            float t;
            t = ef00*wq[ 0] + ef01*wq[ 1] + ef10*wq[ 2] + ef11*wq[ 3];  acc += ab00 * t;
            t = ef00*wq[ 4] + ef01*wq[ 5] + ef10*wq[ 6] + ef11*wq[ 7];  acc += ab01 * t;
            t = ef00*wq[ 8] + ef01*wq[ 9] + ef10*wq[10] + ef11*wq[11];  acc += ab10 * t;
            t = ef00*wq[12] + ef01*wq[13] + ef10*wq[14] + ef11*wq[15];  acc += ab11 * t;
        }
        ob[(size_t)n * (COUT * 2 * NXX * NYY)] = acc;
    }
}

extern "C" void kernel_launch(void* const* d_in, const int* in_sizes, int n_in,
                              void* d_out, int out_size, void* d_ws, size_t ws_size,
                              hipStream_t stream) {
    const float* x    = (const float*)d_in[0];
    const float* w    = (const float*)d_in[1];
    const float* bias = (const float*)d_in[2];
    float* out = (float*)d_out;

    const int grid = NXX * (NYY / YTILE) * NSPLIT;  // 128*4*2 = 1024 blocks
    ttn_kernel<<<grid, 256, 0, stream>>>(x, w, bias, out);
}

// Round 2
// 373.672 us; speedup vs baseline: 1.0716x; 1.0716x over previous
//
#include <hip/hip_runtime.h>

// x: (64, 4, 2, 256, 256) f32 ; tensors: (4,4,128,128,2,2,2,2,2) f32 ;
// bias: (4,128,128,2) f32 ; out: (64,4,2,128,128) f32
// sx=sy=256 even -> ix1=2x+1, iy1=2y+1 (clamp inert).
#define NUMN 64
#define CIN 4
#define COUT 4
#define SX 256
#define SY 256
#define NXX 128
#define NYY 128
#define NSPLIT 2
#define NPER (NUMN / NSPLIT)

// Block: 512 threads = 64 y-lanes (one full wave, contiguous y) x 8 (p,o) groups.
// Every global load instr: 64 lanes x 8 B = 512 B contiguous. 2-way n-unroll
// for 32 loads (16 KB) in flight per wave-iteration.
__global__ __launch_bounds__(512, 4)
void ttn_kernel(const float* __restrict__ x, const float* __restrict__ w,
                const float* __restrict__ bias, float* __restrict__ out)
{
    const int bid = blockIdx.x;
    const int xi = bid % NXX;                    // adjacent blocks -> adjacent 2KB x-regions
    const int yh = (bid / NXX) & 1;              // y half
    const int ns = bid / (NXX * 2);              // n split

    const int tid = threadIdx.x;
    const int yl  = tid & 63;                    // lane within wave = y offset
    const int po  = tid >> 6;                    // wave id = p*2 + o
    const int p   = po >> 1;
    const int o   = po & 1;
    const int y   = yh * 64 + yl;

    // ---- weight preamble: wr[c][q] in registers (q = 8i+4j+2k+l) ----
    // w idx = ((((c*COUT+p)*NXX+xi)*NYY+y)*16 + q)*2 + o ; per (c) the 32
    // floats (q,o interleaved) are contiguous & 128B aligned -> 8 float4 loads.
    float wr[CIN][16];
#pragma unroll
    for (int c = 0; c < CIN; ++c) {
        const float4* wp4 = (const float4*)(w +
            ((size_t)(((c * COUT + p) * NXX + xi) * NYY + y)) * 32);
#pragma unroll
        for (int j = 0; j < 8; ++j) {
            const float4 v = wp4[j];             // covers q=2j (x,y=o0,o1), q=2j+1 (z,w)
            wr[c][2 * j]     = o ? v.y : v.x;
            wr[c][2 * j + 1] = o ? v.w : v.z;
        }
    }
    const float bv = bias[(((p * NXX + xi) * NYY + y) * 2) + o];

    const int ix0 = 2 * xi;
    const int ix1 = 2 * xi + 1;                  // SX even -> always in bounds
    const size_t nstr = (size_t)CIN * 2 * SX * SY;

    const float* xb = x + (size_t)(ns * NPER) * nstr + 2 * y;  // iy0 = 2y
    float* ob = out + (size_t)(ns * NPER) * (COUT * 2 * NXX * NYY)
                    + (size_t)po * (NXX * NYY) + xi * NYY + y;

    for (int n = 0; n < NPER; n += 2) {
        const float* x0 = xb + (size_t)n * nstr;
        const float* x1 = x0 + nstr;

        // issue all 32 loads (2 n-iters x 4 c x 4 corner-pairs) up front
        float2 L0[CIN][4], L1[CIN][4];
#pragma unroll
        for (int c = 0; c < CIN; ++c) {
            const float* xc0 = x0 + c * (2 * SX * SY);
            const float* xc1 = x1 + c * (2 * SX * SY);
            L0[c][0] = *(const float2*)(xc0 + ix0 * SY);        // d=0 {a,e}
            L0[c][1] = *(const float2*)(xc0 + ix1 * SY);        // d=0 {b,f}
            L0[c][2] = *(const float2*)(xc0 + (SX + ix0) * SY); // d=1 {a,e}
            L0[c][3] = *(const float2*)(xc0 + (SX + ix1) * SY); // d=1 {b,f}
            L1[c][0] = *(const float2*)(xc1 + ix0 * SY);
            L1[c][1] = *(const float2*)(xc1 + ix1 * SY);
            L1[c][2] = *(const float2*)(xc1 + (SX + ix0) * SY);
            L1[c][3] = *(const float2*)(xc1 + (SX + ix1) * SY);
        }

        float acc0 = bv, acc1 = bv;
#pragma unroll
        for (int c = 0; c < CIN; ++c) {
            {
                const float a0 = L0[c][0].x, e0 = L0[c][0].y;
                const float b0 = L0[c][1].x, f0 = L0[c][1].y;
                const float a1 = L0[c][2].x, e1 = L0[c][2].y;
                const float b1 = L0[c][3].x, f1 = L0[c][3].y;
                const float ef00 = e0*f0, ef01 = e0*f1, ef10 = e1*f0, ef11 = e1*f1;
                const float ab00 = a0*b0, ab01 = a0*b1, ab10 = a1*b0, ab11 = a1*b1;
                const float* wq = wr[c];
                float t;
                t = ef00*wq[ 0] + ef01*wq[ 1] + ef10*wq[ 2] + ef11*wq[ 3];  acc0 += ab00 * t;
                t = ef00*wq[ 4] + ef01*wq[ 5] + ef10*wq[ 6] + ef11*wq[ 7];  acc0 += ab01 * t;
                t = ef00*wq[ 8] + ef01*wq[ 9] + ef10*wq[10] + ef11*wq[11];  acc0 += ab10 * t;
                t = ef00*wq[12] + ef01*wq[13] + ef10*wq[14] + ef11*wq[15];  acc0 += ab11 * t;
            }
            {
                const float a0 = L1[c][0].x, e0 = L1[c][0].y;
                const float b0 = L1[c][1].x, f0 = L1[c][1].y;
                const float a1 = L1[c][2].x, e1 = L1[c][2].y;
                const float b1 = L1[c][3].x, f1 = L1[c][3].y;
                const float ef00 = e0*f0, ef01 = e0*f1, ef10 = e1*f0, ef11 = e1*f1;
                const float ab00 = a0*b0, ab01 = a0*b1, ab10 = a1*b0, ab11 = a1*b1;
                const float* wq = wr[c];
                float t;
                t = ef00*wq[ 0] + ef01*wq[ 1] + ef10*wq[ 2] + ef11*wq[ 3];  acc1 += ab00 * t;
                t = ef00*wq[ 4] + ef01*wq[ 5] + ef10*wq[ 6] + ef11*wq[ 7];  acc1 += ab01 * t;
                t = ef00*wq[ 8] + ef01*wq[ 9] + ef10*wq[10] + ef11*wq[11];  acc1 += ab10 * t;
                t = ef00*wq[12] + ef01*wq[13] + ef10*wq[14] + ef11*wq[15];  acc1 += ab11 * t;
            }
        }
        ob[(size_t)n       * (COUT * 2 * NXX * NYY)] = acc0;
        ob[(size_t)(n + 1) * (COUT * 2 * NXX * NYY)] = acc1;
    }
}

extern "C" void kernel_launch(void* const* d_in, const int* in_sizes, int n_in,
                              void* d_out, int out_size, void* d_ws, size_t ws_size,
                              hipStream_t stream) {
    const float* x    = (const float*)d_in[0];
    const float* w    = (const float*)d_in[1];
    const float* bias = (const float*)d_in[2];
    float* out = (float*)d_out;

    const int grid = NXX * 2 * NSPLIT;  // 128 xi * 2 y-halves * 2 n-splits = 512
    ttn_kernel<<<grid, 512, 0, stream>>>(x, w, bias, out);
}

// Round 3
// 354.197 us; speedup vs baseline: 1.1305x; 1.0550x over previous
//
#include <hip/hip_runtime.h>

// x: (64, 4, 2, 256, 256) f32 ; tensors: (4,4,128,128,2,2,2,2,2) f32 ;
// bias: (4,128,128,2) f32 ; out: (64,4,2,128,128) f32
// sx=sy=256 even -> ix1=2x+1, iy1=2y+1 (clamp inert).
#define NUMN 64
#define CIN 4
#define COUT 4
#define SX 256
#define SY 256
#define NXX 128
#define NYY 128
#define YTILE 32
#define NSPLIT 2
#define NPER (NUMN / NSPLIT)

// Block: 256 threads = 32 y-lanes x 8 (p,o). Thread holds its 64 weights in
// VGPRs. n-loop unrolled x2 with ALL 32 x-loads batched before use (16 KB in
// flight per wave). __launch_bounds__(256,2): 256-VGPR cap -> NO SPILLS
// (R2's (512,4) cap of 128 spilled wr[] to scratch: WRITE_SIZE 4x, 226us).
__global__ __launch_bounds__(256, 2)
void ttn_kernel(const float* __restrict__ x, const float* __restrict__ w,
                const float* __restrict__ bias, float* __restrict__ out)
{
    const int bid = blockIdx.x;
    const int xi = bid % NXX;                     // concurrent blocks span all xi
    const int yt = (bid / NXX) % (NYY / YTILE);
    const int ns = bid / (NXX * (NYY / YTILE));

    const int tid = threadIdx.x;
    const int yl  = tid & (YTILE - 1);
    const int po  = tid >> 5;                     // p*2 + o
    const int p   = po >> 1;
    const int o   = po & 1;
    const int y   = yt * YTILE + yl;

    // ---- weight preamble: wr[c][q], q = 8i+4j+2k+l (float4 loads) ----
    float wr[CIN][16];
#pragma unroll
    for (int c = 0; c < CIN; ++c) {
        const float4* wp4 = (const float4*)(w +
            ((size_t)(((c * COUT + p) * NXX + xi) * NYY + y)) * 32);
#pragma unroll
        for (int j = 0; j < 8; ++j) {
            const float4 v = wp4[j];
            wr[c][2 * j]     = o ? v.y : v.x;
            wr[c][2 * j + 1] = o ? v.w : v.z;
        }
    }
    const float bv = bias[(((p * NXX + xi) * NYY + y) * 2) + o];

    const int ix0 = 2 * xi;
    const int ix1 = 2 * xi + 1;                   // SX even -> in bounds
    const size_t nstr = (size_t)CIN * 2 * SX * SY;
    const size_t ostr = (size_t)COUT * 2 * NXX * NYY;

    const float* xb = x + (size_t)(ns * NPER) * nstr + 2 * y;   // iy0 = 2y
    float* ob = out + (size_t)(ns * NPER) * ostr
                    + (size_t)po * (NXX * NYY) + xi * NYY + y;

    for (int n = 0; n < NPER; n += 2) {
        // ---- batch all 32 loads (2 n x 4 c x 4 corner-pairs) ----
        float2 L[2][CIN][4];
#pragma unroll
        for (int u = 0; u < 2; ++u) {
            const float* xn = xb + (size_t)(n + u) * nstr;
#pragma unroll
            for (int c = 0; c < CIN; ++c) {
                const float* xc = xn + c * (2 * SX * SY);
                L[u][c][0] = *(const float2*)(xc + ix0 * SY);        // d0 {a,e}
                L[u][c][1] = *(const float2*)(xc + ix1 * SY);        // d0 {b,f}
                L[u][c][2] = *(const float2*)(xc + (SX + ix0) * SY); // d1 {a,e}
                L[u][c][3] = *(const float2*)(xc + (SX + ix1) * SY); // d1 {b,f}
            }
        }

        float acc[2] = {bv, bv};
#pragma unroll
        for (int u = 0; u < 2; ++u) {
#pragma unroll
            for (int c = 0; c < CIN; ++c) {
                const float a0 = L[u][c][0].x, e0 = L[u][c][0].y;
                const float b0 = L[u][c][1].x, f0 = L[u][c][1].y;
                const float a1 = L[u][c][2].x, e1 = L[u][c][2].y;
                const float b1 = L[u][c][3].x, f1 = L[u][c][3].y;
                const float ef00 = e0*f0, ef01 = e0*f1, ef10 = e1*f0, ef11 = e1*f1;
                const float ab00 = a0*b0, ab01 = a0*b1, ab10 = a1*b0, ab11 = a1*b1;
                const float* wq = wr[c];
                float t;
                t = ef00*wq[ 0] + ef01*wq[ 1] + ef10*wq[ 2] + ef11*wq[ 3];  acc[u] += ab00 * t;
                t = ef00*wq[ 4] + ef01*wq[ 5] + ef10*wq[ 6] + ef11*wq[ 7];  acc[u] += ab01 * t;
                t = ef00*wq[ 8] + ef01*wq[ 9] + ef10*wq[10] + ef11*wq[11];  acc[u] += ab10 * t;
                t = ef00*wq[12] + ef01*wq[13] + ef10*wq[14] + ef11*wq[15];  acc[u] += ab11 * t;
            }
        }
        ob[(size_t)n       * ostr] = acc[0];
        ob[(size_t)(n + 1) * ostr] = acc[1];
    }
}

extern "C" void kernel_launch(void* const* d_in, const int* in_sizes, int n_in,
                              void* d_out, int out_size, void* d_ws, size_t ws_size,
                              hipStream_t stream) {
    const float* x    = (const float*)d_in[0];
    const float* w    = (const float*)d_in[1];
    const float* bias = (const float*)d_in[2];
    float* out = (float*)d_out;

    const int grid = NXX * (NYY / YTILE) * NSPLIT;  // 128*4*2 = 1024 blocks
    ttn_kernel<<<grid, 256, 0, stream>>>(x, w, bias, out);
}

// Round 4
// 241.201 us; speedup vs baseline: 1.6601x; 1.4685x over previous
//
#include <hip/hip_runtime.h>

// x: (64, 4, 2, 256, 256) f32 ; tensors: (4,4,128,128,2,2,2,2,2) f32 ;
// bias: (4,128,128,2) f32 ; out: (64,4,2,128,128) f32
// sx=sy=256 even -> ix1=2x+1, iy1=2y+1 (clamp inert).
#define NUMN 64
#define CIN 4
#define COUT 4
#define SX 256
#define SY 256
#define NXX 128
#define NYY 128
#define YTILE 32
#define NSPLIT 2
#define NPER (NUMN / NSPLIT)

// Pipeline: per n, block stages 4 KB of x (16 chunks of 64 floats: (c,d,row))
// into LDS. Each thread prefetches ONE float4 (register), ds_writes it next
// iteration, barrier, then reads its 16 x-values from LDS. Register prefetch
// is not drained by s_barrier -> stays in flight across barrier+compute.
// R1/R3 lesson: per-thread VGPR load batching gets serialized by the register
// allocator (VGPR=92, ~700B in flight/CU); LDS staging can't be sunk.
__global__ __launch_bounds__(256, 4)
void ttn_kernel(const float* __restrict__ x, const float* __restrict__ w,
                const float* __restrict__ bias, float* __restrict__ out)
{
    __shared__ float lds[2][1024];   // 2 x 4 KB

    const int bid = blockIdx.x;
    const int xi = bid % NXX;
    const int yt = (bid / NXX) % (NYY / YTILE);
    const int ns = bid / (NXX * (NYY / YTILE));

    const int tid = threadIdx.x;
    const int yl  = tid & (YTILE - 1);
    const int po  = tid >> 5;                    // p*2 + o
    const int p   = po >> 1;
    const int o   = po & 1;
    const int y   = yt * YTILE + yl;

    // ---- weight preamble: wr[c][q], q = 8i+4j+2k+l (float4 loads) ----
    float wr[CIN][16];
#pragma unroll
    for (int c = 0; c < CIN; ++c) {
        const float4* wp4 = (const float4*)(w +
            ((size_t)(((c * COUT + p) * NXX + xi) * NYY + y)) * 32);
#pragma unroll
        for (int j = 0; j < 8; ++j) {
            const float4 v = wp4[j];
            wr[c][2 * j]     = o ? v.y : v.x;
            wr[c][2 * j + 1] = o ? v.w : v.z;
        }
    }
    const float bv = bias[(((p * NXX + xi) * NYY + y) * 2) + o];

    // ---- staging map: thread -> (chunk mc = (c*2+d)*2 + r, 16B sub-offset) ----
    const int mc   = tid >> 4;                   // 0..15
    const int j0   = (tid & 15) * 4;             // float offset within 64-float chunk
    const int prow = mc >> 1;                    // c*2 + d
    const int r    = mc & 1;                     // which x-row of the pair
    const size_t nstr = (size_t)CIN * 2 * SX * SY;
    const size_t ostr = (size_t)COUT * 2 * NXX * NYY;

    const float* xg = x + (size_t)(ns * NPER) * nstr
                        + ((size_t)prow * SX + (2 * xi + r)) * SY + yt * 64 + j0;
    float* ob = out + (size_t)(ns * NPER) * ostr
                    + (size_t)po * (NXX * NYY) + xi * NYY + y;
    float* ldsw = &lds[0][0] + tid * 4;          // linear ds_write_b128 slot

    float4 P = *(const float4*)xg;               // prefetch n=0

    for (int n = 0; n < NPER; ++n) {
        const int cur = n & 1;
        *(float4*)(ldsw + cur * 1024) = P;       // ds_write_b128

        const int np = (n + 1 < NPER) ? (n + 1) : n;   // clamp (re-load last)
        P = *(const float4*)(xg + (size_t)np * nstr);  // in flight across barrier

        __syncthreads();                         // buf[cur] ready for all

        const float2* l2 = (const float2*)&lds[cur][0];
        float acc = bv;
#pragma unroll
        for (int c = 0; c < CIN; ++c) {
            const float2 ae0 = l2[c * 128 +       yl];   // d0 row0 {a,e}
            const float2 bf0 = l2[c * 128 +  32 + yl];   // d0 row1 {b,f}
            const float2 ae1 = l2[c * 128 +  64 + yl];   // d1 row0 {a,e}
            const float2 bf1 = l2[c * 128 +  96 + yl];   // d1 row1 {b,f}
            const float a0 = ae0.x, e0 = ae0.y, b0 = bf0.x, f0 = bf0.y;
            const float a1 = ae1.x, e1 = ae1.y, b1 = bf1.x, f1 = bf1.y;
            const float ef00 = e0*f0, ef01 = e0*f1, ef10 = e1*f0, ef11 = e1*f1;
            const float ab00 = a0*b0, ab01 = a0*b1, ab10 = a1*b0, ab11 = a1*b1;
            const float* wq = wr[c];
            float t;
            t = ef00*wq[ 0] + ef01*wq[ 1] + ef10*wq[ 2] + ef11*wq[ 3];  acc += ab00 * t;
            t = ef00*wq[ 4] + ef01*wq[ 5] + ef10*wq[ 6] + ef11*wq[ 7];  acc += ab01 * t;
            t = ef00*wq[ 8] + ef01*wq[ 9] + ef10*wq[10] + ef11*wq[11];  acc += ab10 * t;
            t = ef00*wq[12] + ef01*wq[13] + ef10*wq[14] + ef11*wq[15];  acc += ab11 * t;
        }
        ob[(size_t)n * ostr] = acc;
        // single barrier/iter is safe: buf[cur] is rewritten at n+2, and every
        // thread passed barrier n+1 only after consuming its n-reads.
    }
}

extern "C" void kernel_launch(void* const* d_in, const int* in_sizes, int n_in,
                              void* d_out, int out_size, void* d_ws, size_t ws_size,
                              hipStream_t stream) {
    const float* x    = (const float*)d_in[0];
    const float* w    = (const float*)d_in[1];
    const float* bias = (const float*)d_in[2];
    float* out = (float*)d_out;

    const int grid = NXX * (NYY / YTILE) * NSPLIT;  // 128*4*2 = 1024 blocks
    ttn_kernel<<<grid, 256, 0, stream>>>(x, w, bias, out);
}

// Round 5
// 238.995 us; speedup vs baseline: 1.6754x; 1.0092x over previous
//
#include <hip/hip_runtime.h>

// x: (64, 4, 2, 256, 256) f32 ; tensors: (4,4,128,128,2,2,2,2,2) f32 ;
// bias: (4,128,128,2) f32 ; out: (64,4,2,128,128) f32
// sx=sy=256 even -> ix1=2x+1, iy1=2y+1 (clamp inert).
#define NUMN 64
#define CIN 4
#define COUT 4
#define SX 256
#define SY 256
#define NXX 128
#define NYY 128
#define YTILE 32
#define NSPLIT 2
#define NPER (NUMN / NSPLIT)

// LDS pipeline (R4) + two fixes:
//  - __launch_bounds__(256,2): cap 256 VGPR. R4's (256,4) cap=128 spilled
//    wr[] to scratch (VGPR=64, WRITE_SIZE +22.5MB, FETCH +14.5MB). Natural
//    allocation ~110 still gives 4 waves/SIMD = 4 blocks/CU from the HW pool.
//  - 2-deep register prefetch (P0,P1): 2 KB in flight per wave across the
//    barrier; plain VGPR global loads are NOT drained by s_barrier.
__global__ __launch_bounds__(256, 2)
void ttn_kernel(const float* __restrict__ x, const float* __restrict__ w,
                const float* __restrict__ bias, float* __restrict__ out)
{
    __shared__ float lds[2][1024];   // 2 x 4 KB

    const int bid = blockIdx.x;
    const int xi = bid % NXX;
    const int yt = (bid / NXX) % (NYY / YTILE);
    const int ns = bid / (NXX * (NYY / YTILE));

    const int tid = threadIdx.x;
    const int yl  = tid & (YTILE - 1);
    const int po  = tid >> 5;                    // p*2 + o
    const int p   = po >> 1;
    const int o   = po & 1;
    const int y   = yt * YTILE + yl;

    // ---- weight preamble: wr[c][q], q = 8i+4j+2k+l (float4 loads) ----
    float wr[CIN][16];
#pragma unroll
    for (int c = 0; c < CIN; ++c) {
        const float4* wp4 = (const float4*)(w +
            ((size_t)(((c * COUT + p) * NXX + xi) * NYY + y)) * 32);
#pragma unroll
        for (int j = 0; j < 8; ++j) {
            const float4 v = wp4[j];
            wr[c][2 * j]     = o ? v.y : v.x;
            wr[c][2 * j + 1] = o ? v.w : v.z;
        }
    }
    const float bv = bias[(((p * NXX + xi) * NYY + y) * 2) + o];

    // ---- staging map: thread -> (chunk mc = (c*2+d)*2 + r, 16B sub-offset) ----
    const int mc   = tid >> 4;                   // 0..15
    const int j0   = (tid & 15) * 4;             // float offset within 64-float chunk
    const int prow = mc >> 1;                    // c*2 + d
    const int r    = mc & 1;                     // which x-row of the pair
    const size_t nstr = (size_t)CIN * 2 * SX * SY;
    const size_t ostr = (size_t)COUT * 2 * NXX * NYY;

    const float* xg = x + (size_t)(ns * NPER) * nstr
                        + ((size_t)prow * SX + (2 * xi + r)) * SY + yt * 64 + j0;
    float* ob = out + (size_t)(ns * NPER) * ostr
                    + (size_t)po * (NXX * NYY) + xi * NYY + y;
    float* ldsw = &lds[0][0] + tid * 4;          // linear ds_write_b128 slot

    float4 P0 = *(const float4*)xg;              // prefetch n=0
    float4 P1 = *(const float4*)(xg + nstr);     // prefetch n=1

    for (int n = 0; n < NPER; ++n) {
        const int cur = n & 1;
        *(float4*)(ldsw + cur * 1024) = P0;      // ds_write_b128 (waits only P0)
        P0 = P1;
        const int np = (n + 2 < NPER) ? (n + 2) : (NPER - 1);
        P1 = *(const float4*)(xg + (size_t)np * nstr);  // stays in flight

        __syncthreads();                         // buf[cur] ready for all

        const float2* l2 = (const float2*)&lds[cur][0];
        float acc = bv;
#pragma unroll
        for (int c = 0; c < CIN; ++c) {
            const float2 ae0 = l2[c * 128 +       yl];   // d0 row0 {a,e}
            const float2 bf0 = l2[c * 128 +  32 + yl];   // d0 row1 {b,f}
            const float2 ae1 = l2[c * 128 +  64 + yl];   // d1 row0 {a,e}
            const float2 bf1 = l2[c * 128 +  96 + yl];   // d1 row1 {b,f}
            const float a0 = ae0.x, e0 = ae0.y, b0 = bf0.x, f0 = bf0.y;
            const float a1 = ae1.x, e1 = ae1.y, b1 = bf1.x, f1 = bf1.y;
            const float ef00 = e0*f0, ef01 = e0*f1, ef10 = e1*f0, ef11 = e1*f1;
            const float ab00 = a0*b0, ab01 = a0*b1, ab10 = a1*b0, ab11 = a1*b1;
            const float* wq = wr[c];
            float t;
            t = ef00*wq[ 0] + ef01*wq[ 1] + ef10*wq[ 2] + ef11*wq[ 3];  acc += ab00 * t;
            t = ef00*wq[ 4] + ef01*wq[ 5] + ef10*wq[ 6] + ef11*wq[ 7];  acc += ab01 * t;
            t = ef00*wq[ 8] + ef01*wq[ 9] + ef10*wq[10] + ef11*wq[11];  acc += ab10 * t;
            t = ef00*wq[12] + ef01*wq[13] + ef10*wq[14] + ef11*wq[15];  acc += ab11 * t;
        }
        ob[(size_t)n * ostr] = acc;
        // single barrier/iter safe: buf[cur] rewritten only at n+2, after every
        // thread passed barrier n+1, which is after all n-reads completed.
    }
}

extern "C" void kernel_launch(void* const* d_in, const int* in_sizes, int n_in,
                              void* d_out, int out_size, void* d_ws, size_t ws_size,
                              hipStream_t stream) {
    const float* x    = (const float*)d_in[0];
    const float* w    = (const float*)d_in[1];
    const float* bias = (const float*)d_in[2];
    float* out = (float*)d_out;

    const int grid = NXX * (NYY / YTILE) * NSPLIT;  // 128*4*2 = 1024 blocks
    ttn_kernel<<<grid, 256, 0, stream>>>(x, w, bias, out);
}